// Round 1
// baseline (19017.758 us; speedup 1.0000x reference)
//
#include <hip/hip_runtime.h>
#include <hip/hip_cooperative_groups.h>
#include <math.h>

namespace cg = cooperative_groups;

#define BB 64
#define TT 512
#define II 1024
#define HH 1024
#define OO 256

// ---------------------------------------------------------------------------
// Kernel 1: xproj[m][n] = sum_k x[m][k]*W_ih[n][k] + b_ih[n] + b_hh[n]
// M=32768, N=1024, K=1024.  Tile 128x128, BK=16, 256 threads, 8x8 microtile.
// ---------------------------------------------------------------------------
__global__ __launch_bounds__(256) void xproj_gemm(
    const float* __restrict__ X, const float* __restrict__ Wih,
    const float* __restrict__ bih, const float* __restrict__ bhh,
    float* __restrict__ XP) {
  __shared__ float As[16][132];
  __shared__ float Bs[16][132];
  const int tid = threadIdx.x;
  const int m0 = blockIdx.y * 128;
  const int n0 = blockIdx.x * 128;
  const int r  = tid >> 2;
  const int c4 = (tid & 3) << 2;
  const int ty = tid >> 4, tx = tid & 15;
  float acc[8][8] = {};
  const float4* X4 = (const float4*)X;
  const float4* B4 = (const float4*)Wih;

  for (int k0 = 0; k0 < 1024; k0 += 16) {
    const int kq = (k0 >> 2) + (tid & 3);
    float4 a0 = X4[(m0 + r) * 256 + kq];
    float4 a1 = X4[(m0 + 64 + r) * 256 + kq];
    float4 b0 = B4[(n0 + r) * 256 + kq];
    float4 b1 = B4[(n0 + 64 + r) * 256 + kq];
    __syncthreads();  // previous iter's LDS reads done before overwrite
    As[c4 + 0][r] = a0.x; As[c4 + 1][r] = a0.y; As[c4 + 2][r] = a0.z; As[c4 + 3][r] = a0.w;
    As[c4 + 0][r + 64] = a1.x; As[c4 + 1][r + 64] = a1.y; As[c4 + 2][r + 64] = a1.z; As[c4 + 3][r + 64] = a1.w;
    Bs[c4 + 0][r] = b0.x; Bs[c4 + 1][r] = b0.y; Bs[c4 + 2][r] = b0.z; Bs[c4 + 3][r] = b0.w;
    Bs[c4 + 0][r + 64] = b1.x; Bs[c4 + 1][r + 64] = b1.y; Bs[c4 + 2][r + 64] = b1.z; Bs[c4 + 3][r + 64] = b1.w;
    __syncthreads();
#pragma unroll
    for (int kk = 0; kk < 16; ++kk) {
      float4 av0 = *(const float4*)&As[kk][ty << 3];
      float4 av1 = *(const float4*)&As[kk][(ty << 3) + 4];
      float4 bv0 = *(const float4*)&Bs[kk][tx << 3];
      float4 bv1 = *(const float4*)&Bs[kk][(tx << 3) + 4];
      float a_[8] = {av0.x, av0.y, av0.z, av0.w, av1.x, av1.y, av1.z, av1.w};
      float b_[8] = {bv0.x, bv0.y, bv0.z, bv0.w, bv1.x, bv1.y, bv1.z, bv1.w};
#pragma unroll
      for (int i = 0; i < 8; ++i)
#pragma unroll
        for (int j = 0; j < 8; ++j)
          acc[i][j] = fmaf(a_[i], b_[j], acc[i][j]);
    }
  }

  const int nb = n0 + (tx << 3);
  float4 bi0 = *(const float4*)&bih[nb];
  float4 bi1 = *(const float4*)&bih[nb + 4];
  float4 bh0 = *(const float4*)&bhh[nb];
  float4 bh1 = *(const float4*)&bhh[nb + 4];
  float bsum[8] = {bi0.x + bh0.x, bi0.y + bh0.y, bi0.z + bh0.z, bi0.w + bh0.w,
                   bi1.x + bh1.x, bi1.y + bh1.y, bi1.z + bh1.z, bi1.w + bh1.w};
#pragma unroll
  for (int i = 0; i < 8; ++i) {
    const int m = m0 + (ty << 3) + i;
    float4 o0, o1;
    o0.x = acc[i][0] + bsum[0]; o0.y = acc[i][1] + bsum[1];
    o0.z = acc[i][2] + bsum[2]; o0.w = acc[i][3] + bsum[3];
    o1.x = acc[i][4] + bsum[4]; o1.y = acc[i][5] + bsum[5];
    o1.z = acc[i][6] + bsum[6]; o1.w = acc[i][7] + bsum[7];
    *(float4*)&XP[m * 1024 + nb] = o0;
    *(float4*)&XP[m * 1024 + nb + 4] = o1;
  }
}

// ---------------------------------------------------------------------------
// Kernel 2: persistent cooperative recurrence.
// 256 WGs x 256 thr.  wg%8 = batch group (8 batches), wg/8 = hd slice (32 hd).
// LDS: Ws[1024][32] (128KB, W_hh slice transposed) + Hs[1024][8] (32KB).
// Per step: stage h -> compute 4bx4hd microtiles with in-WG k-split(16) ->
// LDS reduce -> tanh(xproj + .) -> write h_next -> grid.sync().
// ---------------------------------------------------------------------------
__global__ __launch_bounds__(256) void rnn_persist(
    const float* __restrict__ Whh, const float* __restrict__ xproj,
    float* __restrict__ hbuf0, float* __restrict__ hbuf1) {
  extern __shared__ float lds[];
  float* Ws = lds;               // [1024][32]
  float* Hs = lds + 1024 * 32;   // [1024][8], reused as red[256][16]

  const int wg = blockIdx.x;
  const int tid = threadIdx.x;
  const int bgrp = wg & 7;
  const int nslc = wg >> 3;
  const int nbase = nslc << 5;   // *32
  const int bbase = bgrp << 3;   // *8

  // ---- one-time: load W_hh slice transposed into LDS ----
  {
    const float4* W4 = (const float4*)Whh;
    for (int f = tid; f < 32 * 256; f += 256) {
      int hl = f >> 8;       // 0..31 local hd
      int kq = f & 255;      // float4 index along k
      float4 v = W4[(nbase + hl) * 256 + kq];
      int k = kq << 2;
      Ws[(k + 0) * 32 + hl] = v.x;
      Ws[(k + 1) * 32 + hl] = v.y;
      Ws[(k + 2) * 32 + hl] = v.z;
      Ws[(k + 3) * 32 + hl] = v.w;
    }
  }
  // ---- zero h0 slice (h starts at 0) ----
  {
    int b_o = tid >> 5, n_o = tid & 31;
    hbuf0[(bbase + b_o) * 1024 + nbase + n_o] = 0.0f;
  }
  cg::grid_group grid = cg::this_grid();
  grid.sync();

  const int kp  = tid >> 4;          // 0..15 k-chunk
  const int hd8 = (tid >> 1) & 7;    // 0..7  -> hd = hd8*4
  const int b4  = tid & 1;           // 0..1  -> b  = b4*4
  const int b_o = tid >> 5, n_o = tid & 31;  // output this thread reduces
  const int rtid = ((n_o >> 2) << 1) | (b_o >> 2);
  const int rsub = ((b_o & 3) << 2) | (n_o & 3);

  float* hc = hbuf0;
  float* hn = hbuf1;

#pragma unroll 1
  for (int t = 0; t < 512; ++t) {
    // 1. stage h rows [bbase, bbase+8) transposed into Hs[k][b]
    const float4* h4 = (const float4*)(hc + bbase * 1024);
    for (int f = tid; f < 2048; f += 256) {
      int b = f >> 8, kq = f & 255;
      float4 v = h4[b * 256 + kq];
      int k = kq << 2;
      Hs[(k + 0) * 8 + b] = v.x;
      Hs[(k + 1) * 8 + b] = v.y;
      Hs[(k + 2) * 8 + b] = v.z;
      Hs[(k + 3) * 8 + b] = v.w;
    }
    __syncthreads();

    // 2. compute 4x4 partial over this thread's 64-k chunk
    float acc[4][4] = {};
    const int kb = kp << 6;
#pragma unroll 8
    for (int u = 0; u < 64; ++u) {
      int k = kb + u;
      float4 hv = *(const float4*)&Hs[k * 8 + (b4 << 2)];
      float4 wv = *(const float4*)&Ws[k * 32 + (hd8 << 2)];
      acc[0][0] = fmaf(hv.x, wv.x, acc[0][0]); acc[0][1] = fmaf(hv.x, wv.y, acc[0][1]);
      acc[0][2] = fmaf(hv.x, wv.z, acc[0][2]); acc[0][3] = fmaf(hv.x, wv.w, acc[0][3]);
      acc[1][0] = fmaf(hv.y, wv.x, acc[1][0]); acc[1][1] = fmaf(hv.y, wv.y, acc[1][1]);
      acc[1][2] = fmaf(hv.y, wv.z, acc[1][2]); acc[1][3] = fmaf(hv.y, wv.w, acc[1][3]);
      acc[2][0] = fmaf(hv.z, wv.x, acc[2][0]); acc[2][1] = fmaf(hv.z, wv.y, acc[2][1]);
      acc[2][2] = fmaf(hv.z, wv.z, acc[2][2]); acc[2][3] = fmaf(hv.z, wv.w, acc[2][3]);
      acc[3][0] = fmaf(hv.w, wv.x, acc[3][0]); acc[3][1] = fmaf(hv.w, wv.y, acc[3][1]);
      acc[3][2] = fmaf(hv.w, wv.z, acc[3][2]); acc[3][3] = fmaf(hv.w, wv.w, acc[3][3]);
    }
    __syncthreads();  // done reading Hs; reuse as reduction scratch

    // 3. spill partials
    float* red = Hs;
    float* mine = red + tid * 16;
#pragma unroll
    for (int i = 0; i < 4; ++i)
#pragma unroll
      for (int j = 0; j < 4; ++j)
        mine[(i << 2) + j] = acc[i][j];
    __syncthreads();

    // 4. reduce over 16 k-chunks, add xproj, tanh, write h_next
    float sum = 0.0f;
#pragma unroll
    for (int kp2 = 0; kp2 < 16; ++kp2)
      sum += red[(((kp2 << 4) | rtid) << 4) | rsub];
    const int gb = bbase + b_o;
    const int gn = nbase + n_o;
    float val = tanhf(xproj[(gb * 512 + t) * 1024 + gn] + sum);
    hn[gb * 1024 + gn] = val;

    grid.sync();
    float* tmp = hc; hc = hn; hn = tmp;
  }
  // 512 swaps (even) -> final h resides in hbuf0
}

// ---------------------------------------------------------------------------
// Kernel 3: small head GEMM: C[64][N] = A[64][K] * Bm[N][K]^T + bias[N]
// Tile 64x64, BK=16, 256 thr, 4x4 microtile.  grid.x = N/64.
// ---------------------------------------------------------------------------
__global__ __launch_bounds__(256) void head_gemm(
    const float* __restrict__ A, const float* __restrict__ Bm,
    const float* __restrict__ bias, float* __restrict__ C, int N, int K) {
  __shared__ float As[16][68];
  __shared__ float Bs[16][68];
  const int tid = threadIdx.x;
  const int n0 = blockIdx.x * 64;
  const int r = tid >> 2;
  const int c4 = (tid & 3) << 2;
  const int ty = tid >> 4, tx = tid & 15;
  float acc[4][4] = {};
  const float4* A4 = (const float4*)A;
  const float4* B4 = (const float4*)Bm;
  const int K4 = K >> 2;

  for (int k0 = 0; k0 < K; k0 += 16) {
    const int kq = (k0 >> 2) + (tid & 3);
    float4 av = A4[r * K4 + kq];
    float4 bv = B4[(n0 + r) * K4 + kq];
    __syncthreads();
    As[c4 + 0][r] = av.x; As[c4 + 1][r] = av.y; As[c4 + 2][r] = av.z; As[c4 + 3][r] = av.w;
    Bs[c4 + 0][r] = bv.x; Bs[c4 + 1][r] = bv.y; Bs[c4 + 2][r] = bv.z; Bs[c4 + 3][r] = bv.w;
    __syncthreads();
#pragma unroll
    for (int kk = 0; kk < 16; ++kk) {
      float4 a = *(const float4*)&As[kk][ty << 2];
      float4 b = *(const float4*)&Bs[kk][tx << 2];
      acc[0][0] = fmaf(a.x, b.x, acc[0][0]); acc[0][1] = fmaf(a.x, b.y, acc[0][1]);
      acc[0][2] = fmaf(a.x, b.z, acc[0][2]); acc[0][3] = fmaf(a.x, b.w, acc[0][3]);
      acc[1][0] = fmaf(a.y, b.x, acc[1][0]); acc[1][1] = fmaf(a.y, b.y, acc[1][1]);
      acc[1][2] = fmaf(a.y, b.z, acc[1][2]); acc[1][3] = fmaf(a.y, b.w, acc[1][3]);
      acc[2][0] = fmaf(a.z, b.x, acc[2][0]); acc[2][1] = fmaf(a.z, b.y, acc[2][1]);
      acc[2][2] = fmaf(a.z, b.z, acc[2][2]); acc[2][3] = fmaf(a.z, b.w, acc[2][3]);
      acc[3][0] = fmaf(a.w, b.x, acc[3][0]); acc[3][1] = fmaf(a.w, b.y, acc[3][1]);
      acc[3][2] = fmaf(a.w, b.z, acc[3][2]); acc[3][3] = fmaf(a.w, b.w, acc[3][3]);
    }
  }
  float4 bv = *(const float4*)&bias[n0 + (tx << 2)];
  float bs[4] = {bv.x, bv.y, bv.z, bv.w};
#pragma unroll
  for (int i = 0; i < 4; ++i) {
    float4 o;
    o.x = acc[i][0] + bs[0]; o.y = acc[i][1] + bs[1];
    o.z = acc[i][2] + bs[2]; o.w = acc[i][3] + bs[3];
    *(float4*)&C[((ty << 2) + i) * N + n0 + (tx << 2)] = o;
  }
}

// ---------------------------------------------------------------------------
extern "C" void kernel_launch(void* const* d_in, const int* in_sizes, int n_in,
                              void* d_out, int out_size, void* d_ws, size_t ws_size,
                              hipStream_t stream) {
  const float* x    = (const float*)d_in[0];
  const float* Wih  = (const float*)d_in[1];
  const float* bih  = (const float*)d_in[2];
  const float* Whh  = (const float*)d_in[3];
  const float* bhh  = (const float*)d_in[4];
  const float* Wfc  = (const float*)d_in[5];
  const float* bfc  = (const float*)d_in[6];
  const float* Wclf = (const float*)d_in[7];
  const float* bclf = (const float*)d_in[8];
  float* out = (float*)d_out;

  float* ws = (float*)d_ws;
  float* xp = ws;                      // 33,554,432 f (128 MB)
  float* h0 = ws + 33554432;           // 65,536 f
  float* h1 = h0 + 65536;              // 65,536 f
  float* y1 = h1 + 65536;              // 65,536 f

  // Phase 1: input projection for all timesteps
  xproj_gemm<<<dim3(8, 256), 256, 0, stream>>>(x, Wih, bih, bhh, xp);

  // Phase 2: persistent cooperative recurrence (160 KiB dynamic LDS)
  hipFuncSetAttribute((const void*)rnn_persist,
                      hipFuncAttributeMaxDynamicSharedMemorySize, 163840);
  void* args[] = {(void*)&Whh, (void*)&xp, (void*)&h0, (void*)&h1};
  hipLaunchCooperativeKernel((const void*)rnn_persist, dim3(256), dim3(256),
                             args, 163840, stream);

  // Phase 3: head (final h is in h0 after an even number of swaps)
  head_gemm<<<dim3(16), 256, 0, stream>>>(h0, Wfc, bfc, y1, 1024, 1024);
  head_gemm<<<dim3(4),  256, 0, stream>>>(y1, Wclf, bclf, out, 256, 1024);
}

// Round 5
// 15856.598 us; speedup vs baseline: 1.1994x; 1.1994x over previous
//
#include <hip/hip_runtime.h>
#include <hip/hip_cooperative_groups.h>
#include <math.h>

// ---------------------------------------------------------------------------
// Kernel 1: xproj[t][b][n] = sum_k x[b][t][k]*W_ih[n][k] + b_ih[n] + b_hh[n]
// Output TRANSPOSED to [T][B][H] so the recurrence reads contiguous slabs.
// M=32768 (m = b*512+t), N=1024, K=1024. 128x128 tile, BK=16, 8x8 microtile.
// ---------------------------------------------------------------------------
__global__ __launch_bounds__(256) void xproj_gemm(
    const float* __restrict__ X, const float* __restrict__ Wih,
    const float* __restrict__ bih, const float* __restrict__ bhh,
    float* __restrict__ XP) {
  __shared__ float As[16][132];
  __shared__ float Bs[16][132];
  const int tid = threadIdx.x;
  const int m0 = blockIdx.y * 128;
  const int n0 = blockIdx.x * 128;
  const int r  = tid >> 2;
  const int c4 = (tid & 3) << 2;
  const int ty = tid >> 4, tx = tid & 15;
  float acc[8][8] = {};
  const float4* X4 = (const float4*)X;
  const float4* B4 = (const float4*)Wih;

  for (int k0 = 0; k0 < 1024; k0 += 16) {
    const int kq = (k0 >> 2) + (tid & 3);
    float4 a0 = X4[(m0 + r) * 256 + kq];
    float4 a1 = X4[(m0 + 64 + r) * 256 + kq];
    float4 b0 = B4[(n0 + r) * 256 + kq];
    float4 b1 = B4[(n0 + 64 + r) * 256 + kq];
    __syncthreads();
    As[c4 + 0][r] = a0.x; As[c4 + 1][r] = a0.y; As[c4 + 2][r] = a0.z; As[c4 + 3][r] = a0.w;
    As[c4 + 0][r + 64] = a1.x; As[c4 + 1][r + 64] = a1.y; As[c4 + 2][r + 64] = a1.z; As[c4 + 3][r + 64] = a1.w;
    Bs[c4 + 0][r] = b0.x; Bs[c4 + 1][r] = b0.y; Bs[c4 + 2][r] = b0.z; Bs[c4 + 3][r] = b0.w;
    Bs[c4 + 0][r + 64] = b1.x; Bs[c4 + 1][r + 64] = b1.y; Bs[c4 + 2][r + 64] = b1.z; Bs[c4 + 3][r + 64] = b1.w;
    __syncthreads();
#pragma unroll
    for (int kk = 0; kk < 16; ++kk) {
      float4 av0 = *(const float4*)&As[kk][ty << 3];
      float4 av1 = *(const float4*)&As[kk][(ty << 3) + 4];
      float4 bv0 = *(const float4*)&Bs[kk][tx << 3];
      float4 bv1 = *(const float4*)&Bs[kk][(tx << 3) + 4];
      float a_[8] = {av0.x, av0.y, av0.z, av0.w, av1.x, av1.y, av1.z, av1.w};
      float b_[8] = {bv0.x, bv0.y, bv0.z, bv0.w, bv1.x, bv1.y, bv1.z, bv1.w};
#pragma unroll
      for (int i = 0; i < 8; ++i)
#pragma unroll
        for (int j = 0; j < 8; ++j)
          acc[i][j] = fmaf(a_[i], b_[j], acc[i][j]);
    }
  }

  const int nb = n0 + (tx << 3);
  float4 bi0 = *(const float4*)&bih[nb];
  float4 bi1 = *(const float4*)&bih[nb + 4];
  float4 bh0 = *(const float4*)&bhh[nb];
  float4 bh1 = *(const float4*)&bhh[nb + 4];
  float bsum[8] = {bi0.x + bh0.x, bi0.y + bh0.y, bi0.z + bh0.z, bi0.w + bh0.w,
                   bi1.x + bh1.x, bi1.y + bh1.y, bi1.z + bh1.z, bi1.w + bh1.w};
#pragma unroll
  for (int i = 0; i < 8; ++i) {
    const int m = m0 + (ty << 3) + i;
    const int b = m >> 9, t = m & 511;   // X row m = b*512 + t
    float4 o0, o1;
    o0.x = acc[i][0] + bsum[0]; o0.y = acc[i][1] + bsum[1];
    o0.z = acc[i][2] + bsum[2]; o0.w = acc[i][3] + bsum[3];
    o1.x = acc[i][4] + bsum[4]; o1.y = acc[i][5] + bsum[5];
    o1.z = acc[i][6] + bsum[6]; o1.w = acc[i][7] + bsum[7];
    float* dst = &XP[((t << 6) + b) * 1024 + nb];   // [T][B][H]
    *(float4*)dst = o0;
    *(float4*)(dst + 4) = o1;
  }
}

// ---------------------------------------------------------------------------
// Kernel 2: persistent recurrence with PER-BATCH-GROUP sync (8 domains x 32 WG).
// wg&7 = batch group (8 batches), wg>>3 = hd slice (32 wide).
// LDS: Ws[1024][32] fp32 (128KB, W_hh^T slice) + Hs[8][1024] (32KB, XOR-swizzled
// 16B blocks; aliased as reduction scratch stride-20).
// ---------------------------------------------------------------------------
#define DO_B(i, hv) \
  acc[i][0]=fmaf(hv.x,w0.x,acc[i][0]); acc[i][0]=fmaf(hv.y,w1.x,acc[i][0]); \
  acc[i][0]=fmaf(hv.z,w2.x,acc[i][0]); acc[i][0]=fmaf(hv.w,w3.x,acc[i][0]); \
  acc[i][1]=fmaf(hv.x,w0.y,acc[i][1]); acc[i][1]=fmaf(hv.y,w1.y,acc[i][1]); \
  acc[i][1]=fmaf(hv.z,w2.y,acc[i][1]); acc[i][1]=fmaf(hv.w,w3.y,acc[i][1]); \
  acc[i][2]=fmaf(hv.x,w0.z,acc[i][2]); acc[i][2]=fmaf(hv.y,w1.z,acc[i][2]); \
  acc[i][2]=fmaf(hv.z,w2.z,acc[i][2]); acc[i][2]=fmaf(hv.w,w3.z,acc[i][2]); \
  acc[i][3]=fmaf(hv.x,w0.w,acc[i][3]); acc[i][3]=fmaf(hv.y,w1.w,acc[i][3]); \
  acc[i][3]=fmaf(hv.z,w2.w,acc[i][3]); acc[i][3]=fmaf(hv.w,w3.w,acc[i][3]);

__global__ __launch_bounds__(256) void rnn_persist(
    const float* __restrict__ Whh, const float* __restrict__ xproj,
    float* __restrict__ hbuf0, float* __restrict__ hbuf1,
    unsigned* __restrict__ cnt) {
  extern __shared__ float lds[];
  float* Ws = lds;                  // [1024][32] transposed W slice
  float* Hs = lds + 1024 * 32;      // [8][1024] b-major, swizzled blocks
  float* red = Hs;                  // alias (needs 256*20 = 5120 f)
  float4* Hs4 = (float4*)Hs;
  const float4* Ws4 = (const float4*)Ws;

  const int tid = threadIdx.x;
  const int wg = blockIdx.x;
  const int bgrp = wg & 7;
  const int nslc = wg >> 3;
  const int nbase = nslc << 5;
  const int bbase = bgrp << 3;
  unsigned* mycnt = cnt + bgrp * 64;   // 256B apart

  // ---- one-time: W_hh slice transposed into LDS (Ws[k][hl] = W[nbase+hl][k])
  {
    const float4* W4 = (const float4*)Whh;
    for (int f = tid; f < 32 * 256; f += 256) {
      int hl = f >> 8;
      int kq = f & 255;
      float4 v = W4[(nbase + hl) * 256 + kq];
      int k = kq << 2;
      Ws[(k + 0) * 32 + hl] = v.x;
      Ws[(k + 1) * 32 + hl] = v.y;
      Ws[(k + 2) * 32 + hl] = v.z;
      Ws[(k + 3) * 32 + hl] = v.w;
    }
  }
  // ---- zero h0 slice ----
  const int b_o = tid >> 5, n_o = tid & 31;
  const int gb = bbase + b_o, gn = nbase + n_o;
  hbuf0[gb * 1024 + gn] = 0.0f;

  unsigned phase = 0;
  auto bsync = [&](unsigned ph) {
    __threadfence();          // release own stores (device scope)
    __syncthreads();          // all threads of WG fenced before arrival
    if (tid == 0) {
      __hip_atomic_fetch_add(mycnt, 1u, __ATOMIC_RELEASE, __HIP_MEMORY_SCOPE_AGENT);
      const unsigned tgt = 32u * ph;
      while (__hip_atomic_load(mycnt, __ATOMIC_ACQUIRE, __HIP_MEMORY_SCOPE_AGENT) < tgt)
        __builtin_amdgcn_s_sleep(1);
      __threadfence();        // acquire: invalidate stale cache lines
    }
    __syncthreads();          // fan-out
  };
  bsync(++phase);             // Ws staged, h0 zeroed domain-wide

  const int kp  = tid >> 4;          // 0..15 k-chunk (64 wide)
  const int hd8 = (tid >> 1) & 7;    // hd block
  const int b4  = tid & 1;           // batch half
  // reduction read base for output (b_o, n_o)
  const int cbase = (((n_o >> 2) << 1) | (b_o >> 2)) * 20 + ((b_o & 3) << 2) + (n_o & 3);

  float* hc = hbuf0;
  float* hn = hbuf1;

#pragma unroll 1
  for (int t = 0; t < 512; ++t) {
    // prefetch this step's xproj value (coalesced, [T][B][H])
    const float xpv = xproj[((t << 6) + gb) * 1024 + gn];

    // 1. stage h rows [bbase..bbase+8) b-major into Hs (block-XOR swizzle)
    const float4* h4 = (const float4*)(hc + (bbase << 10));
#pragma unroll
    for (int it = 0; it < 8; ++it) {
      const int kq = tid;                       // f4 index along k
      float4 v = h4[it * 256 + kq];
      Hs4[((it << 8) | kq) ^ ((kq >> 4) & 7)] = v;
    }
    __syncthreads();

    // 2. 4b x 4hd microtile over this thread's 64-k chunk, k-vectorized by 4
    float acc[4][4] = {};
#pragma unroll
    for (int q = 0; q < 16; ++q) {
      const int k0 = (kp << 6) + (q << 2);
      const int kb = k0 >> 2;
      const int sw = kp & 7;
      float4 h0v = Hs4[((((b4 << 2) + 0) << 8) | kb) ^ sw];
      float4 h1v = Hs4[((((b4 << 2) + 1) << 8) | kb) ^ sw];
      float4 h2v = Hs4[((((b4 << 2) + 2) << 8) | kb) ^ sw];
      float4 h3v = Hs4[((((b4 << 2) + 3) << 8) | kb) ^ sw];
      float4 w0 = Ws4[(k0 + 0) * 8 + hd8];
      float4 w1 = Ws4[(k0 + 1) * 8 + hd8];
      float4 w2 = Ws4[(k0 + 2) * 8 + hd8];
      float4 w3 = Ws4[(k0 + 3) * 8 + hd8];
      DO_B(0, h0v)
      DO_B(1, h1v)
      DO_B(2, h2v)
      DO_B(3, h3v)
    }
    __syncthreads();   // everyone done reading Hs before red overwrites it

    // 3. spill partials, stride 20 floats (bank-balanced b128 stores)
    float4* m4 = (float4*)(red + tid * 20);
    m4[0] = make_float4(acc[0][0], acc[0][1], acc[0][2], acc[0][3]);
    m4[1] = make_float4(acc[1][0], acc[1][1], acc[1][2], acc[1][3]);
    m4[2] = make_float4(acc[2][0], acc[2][1], acc[2][2], acc[2][3]);
    m4[3] = make_float4(acc[3][0], acc[3][1], acc[3][2], acc[3][3]);
    __syncthreads();

    // 4. reduce 16 k-chunks, tanh, write h_next
    float sum = 0.0f;
#pragma unroll
    for (int kp2 = 0; kp2 < 16; ++kp2)
      sum += red[kp2 * 320 + cbase];
    hn[(gb << 10) + gn] = tanhf(xpv + sum);

    bsync(++phase);    // domain barrier: h_next fully visible
    float* tmp = hc; hc = hn; hn = tmp;
  }
  // final h in hbuf0 (even number of swaps)
}

// ---------------------------------------------------------------------------
// Kernel 3: head GEMM: C[64][N] = A[64][K] * Bm[N][K]^T + bias[N]
// ---------------------------------------------------------------------------
__global__ __launch_bounds__(256) void head_gemm(
    const float* __restrict__ A, const float* __restrict__ Bm,
    const float* __restrict__ bias, float* __restrict__ C, int N, int K) {
  __shared__ float As[16][68];
  __shared__ float Bs[16][68];
  const int tid = threadIdx.x;
  const int n0 = blockIdx.x * 64;
  const int r = tid >> 2;
  const int c4 = (tid & 3) << 2;
  const int ty = tid >> 4, tx = tid & 15;
  float acc[4][4] = {};
  const float4* A4 = (const float4*)A;
  const float4* B4 = (const float4*)Bm;
  const int K4 = K >> 2;

  for (int k0 = 0; k0 < K; k0 += 16) {
    const int kq = (k0 >> 2) + (tid & 3);
    float4 av = A4[r * K4 + kq];
    float4 bv = B4[(n0 + r) * K4 + kq];
    __syncthreads();
    As[c4 + 0][r] = av.x; As[c4 + 1][r] = av.y; As[c4 + 2][r] = av.z; As[c4 + 3][r] = av.w;
    Bs[c4 + 0][r] = bv.x; Bs[c4 + 1][r] = bv.y; Bs[c4 + 2][r] = bv.z; Bs[c4 + 3][r] = bv.w;
    __syncthreads();
#pragma unroll
    for (int kk = 0; kk < 16; ++kk) {
      float4 a = *(const float4*)&As[kk][ty << 2];
      float4 b = *(const float4*)&Bs[kk][tx << 2];
      acc[0][0] = fmaf(a.x, b.x, acc[0][0]); acc[0][1] = fmaf(a.x, b.y, acc[0][1]);
      acc[0][2] = fmaf(a.x, b.z, acc[0][2]); acc[0][3] = fmaf(a.x, b.w, acc[0][3]);
      acc[1][0] = fmaf(a.y, b.x, acc[1][0]); acc[1][1] = fmaf(a.y, b.y, acc[1][1]);
      acc[1][2] = fmaf(a.y, b.z, acc[1][2]); acc[1][3] = fmaf(a.y, b.w, acc[1][3]);
      acc[2][0] = fmaf(a.z, b.x, acc[2][0]); acc[2][1] = fmaf(a.z, b.y, acc[2][1]);
      acc[2][2] = fmaf(a.z, b.z, acc[2][2]); acc[2][3] = fmaf(a.z, b.w, acc[2][3]);
      acc[3][0] = fmaf(a.w, b.x, acc[3][0]); acc[3][1] = fmaf(a.w, b.y, acc[3][1]);
      acc[3][2] = fmaf(a.w, b.z, acc[3][2]); acc[3][3] = fmaf(a.w, b.w, acc[3][3]);
    }
  }
  float4 bv = *(const float4*)&bias[n0 + (tx << 2)];
  float bs[4] = {bv.x, bv.y, bv.z, bv.w};
#pragma unroll
  for (int i = 0; i < 4; ++i) {
    float4 o;
    o.x = acc[i][0] + bs[0]; o.y = acc[i][1] + bs[1];
    o.z = acc[i][2] + bs[2]; o.w = acc[i][3] + bs[3];
    *(float4*)&C[((ty << 2) + i) * N + n0 + (tx << 2)] = o;
  }
}

// ---------------------------------------------------------------------------
extern "C" void kernel_launch(void* const* d_in, const int* in_sizes, int n_in,
                              void* d_out, int out_size, void* d_ws, size_t ws_size,
                              hipStream_t stream) {
  const float* x    = (const float*)d_in[0];
  const float* Wih  = (const float*)d_in[1];
  const float* bih  = (const float*)d_in[2];
  const float* Whh  = (const float*)d_in[3];
  const float* bhh  = (const float*)d_in[4];
  const float* Wfc  = (const float*)d_in[5];
  const float* bfc  = (const float*)d_in[6];
  const float* Wclf = (const float*)d_in[7];
  const float* bclf = (const float*)d_in[8];
  float* out = (float*)d_out;

  float* ws = (float*)d_ws;
  float* xp = ws;                      // 33,554,432 f (128 MB), layout [T][B][H]
  float* h0 = ws + 33554432;           // 65,536 f
  float* h1 = h0 + 65536;              // 65,536 f
  float* y1 = h1 + 65536;              // 65,536 f

  // sync counters live in d_out's first 2KB (poisoned each call; heads
  // overwrite all of d_out afterwards)
  unsigned* cnt = (unsigned*)d_out;
  hipMemsetAsync(cnt, 0, 8 * 64 * sizeof(unsigned), stream);

  // Phase 1: input projection, transposed to [T][B][H]
  xproj_gemm<<<dim3(8, 256), 256, 0, stream>>>(x, Wih, bih, bhh, xp);

  // Phase 2: persistent recurrence (160 KiB dynamic LDS, coop for residency)
  hipFuncSetAttribute((const void*)rnn_persist,
                      hipFuncAttributeMaxDynamicSharedMemorySize, 163840);
  void* args[] = {(void*)&Whh, (void*)&xp, (void*)&h0, (void*)&h1, (void*)&cnt};
  hipLaunchCooperativeKernel((const void*)rnn_persist, dim3(256), dim3(256),
                             args, 163840, stream);

  // Phase 3: head
  head_gemm<<<dim3(16), 256, 0, stream>>>(h0, Wfc, bfc, y1, 1024, 1024);
  head_gemm<<<dim3(4),  256, 0, stream>>>(y1, Wclf, bclf, out, 256, 1024);
}

// Round 7
// 4778.770 us; speedup vs baseline: 3.9796x; 3.3181x over previous
//
#include <hip/hip_runtime.h>
#include <math.h>

// ---------------------------------------------------------------------------
// Kernel 1: xproj[t][b][n] = sum_k x[b][t][k]*W_ih[n][k] + b_ih[n] + b_hh[n]
// Output TRANSPOSED to [T][B][H] so the recurrence reads contiguous slabs.
// M=32768 (m = b*512+t), N=1024, K=1024. 128x128 tile, BK=16, 8x8 microtile.
// ---------------------------------------------------------------------------
__global__ __launch_bounds__(256) void xproj_gemm(
    const float* __restrict__ X, const float* __restrict__ Wih,
    const float* __restrict__ bih, const float* __restrict__ bhh,
    float* __restrict__ XP) {
  __shared__ float As[16][132];
  __shared__ float Bs[16][132];
  const int tid = threadIdx.x;
  const int m0 = blockIdx.y * 128;
  const int n0 = blockIdx.x * 128;
  const int r  = tid >> 2;
  const int c4 = (tid & 3) << 2;
  const int ty = tid >> 4, tx = tid & 15;
  float acc[8][8] = {};
  const float4* X4 = (const float4*)X;
  const float4* B4 = (const float4*)Wih;

  for (int k0 = 0; k0 < 1024; k0 += 16) {
    const int kq = (k0 >> 2) + (tid & 3);
    float4 a0 = X4[(m0 + r) * 256 + kq];
    float4 a1 = X4[(m0 + 64 + r) * 256 + kq];
    float4 b0 = B4[(n0 + r) * 256 + kq];
    float4 b1 = B4[(n0 + 64 + r) * 256 + kq];
    __syncthreads();
    As[c4 + 0][r] = a0.x; As[c4 + 1][r] = a0.y; As[c4 + 2][r] = a0.z; As[c4 + 3][r] = a0.w;
    As[c4 + 0][r + 64] = a1.x; As[c4 + 1][r + 64] = a1.y; As[c4 + 2][r + 64] = a1.z; As[c4 + 3][r + 64] = a1.w;
    Bs[c4 + 0][r] = b0.x; Bs[c4 + 1][r] = b0.y; Bs[c4 + 2][r] = b0.z; Bs[c4 + 3][r] = b0.w;
    Bs[c4 + 0][r + 64] = b1.x; Bs[c4 + 1][r + 64] = b1.y; Bs[c4 + 2][r + 64] = b1.z; Bs[c4 + 3][r + 64] = b1.w;
    __syncthreads();
#pragma unroll
    for (int kk = 0; kk < 16; ++kk) {
      float4 av0 = *(const float4*)&As[kk][ty << 3];
      float4 av1 = *(const float4*)&As[kk][(ty << 3) + 4];
      float4 bv0 = *(const float4*)&Bs[kk][tx << 3];
      float4 bv1 = *(const float4*)&Bs[kk][(tx << 3) + 4];
      float a_[8] = {av0.x, av0.y, av0.z, av0.w, av1.x, av1.y, av1.z, av1.w};
      float b_[8] = {bv0.x, bv0.y, bv0.z, bv0.w, bv1.x, bv1.y, bv1.z, bv1.w};
#pragma unroll
      for (int i = 0; i < 8; ++i)
#pragma unroll
        for (int j = 0; j < 8; ++j)
          acc[i][j] = fmaf(a_[i], b_[j], acc[i][j]);
    }
  }

  const int nb = n0 + (tx << 3);
  float4 bi0 = *(const float4*)&bih[nb];
  float4 bi1 = *(const float4*)&bih[nb + 4];
  float4 bh0 = *(const float4*)&bhh[nb];
  float4 bh1 = *(const float4*)&bhh[nb + 4];
  float bsum[8] = {bi0.x + bh0.x, bi0.y + bh0.y, bi0.z + bh0.z, bi0.w + bh0.w,
                   bi1.x + bh1.x, bi1.y + bh1.y, bi1.z + bh1.z, bi1.w + bh1.w};
#pragma unroll
  for (int i = 0; i < 8; ++i) {
    const int m = m0 + (ty << 3) + i;
    const int b = m >> 9, t = m & 511;   // X row m = b*512 + t
    float4 o0, o1;
    o0.x = acc[i][0] + bsum[0]; o0.y = acc[i][1] + bsum[1];
    o0.z = acc[i][2] + bsum[2]; o0.w = acc[i][3] + bsum[3];
    o1.x = acc[i][4] + bsum[4]; o1.y = acc[i][5] + bsum[5];
    o1.z = acc[i][6] + bsum[6]; o1.w = acc[i][7] + bsum[7];
    float* dst = &XP[((t << 6) + b) * 1024 + nb];   // [T][B][H]
    *(float4*)dst = o0;
    *(float4*)(dst + 4) = o1;
  }
}

// ---------------------------------------------------------------------------
// Kernel 2: persistent recurrence, FLAG-BASED all-gather (8 domains x 32 WG).
// wg&7 = batch group (8 batches), wg>>3 = hd slice (32 wide).
// All cross-WG data (h bufs) via relaxed AGENT-scope atomics (L2-bypass per
// access -> no fences, no RMWs, no wbl2/inv). Publish: syncthreads (vmcnt
// drain = data acked at L3) then one relaxed flag store. Wait: wave0 spins
// on 32 flags. Double-buffer parity race-free: flags>=t+1 implies all
// peers finished staging h(t), hence done reading h(t-1)'s buffer.
// LDS: Ws[1024][32] (128KB W_hh^T slice) + Hs[8][1024] (32KB, swizzled).
// ---------------------------------------------------------------------------
#define DO_B(i, hv) \
  acc[i][0]=fmaf(hv.x,w0.x,acc[i][0]); acc[i][0]=fmaf(hv.y,w1.x,acc[i][0]); \
  acc[i][0]=fmaf(hv.z,w2.x,acc[i][0]); acc[i][0]=fmaf(hv.w,w3.x,acc[i][0]); \
  acc[i][1]=fmaf(hv.x,w0.y,acc[i][1]); acc[i][1]=fmaf(hv.y,w1.y,acc[i][1]); \
  acc[i][1]=fmaf(hv.z,w2.y,acc[i][1]); acc[i][1]=fmaf(hv.w,w3.y,acc[i][1]); \
  acc[i][2]=fmaf(hv.x,w0.z,acc[i][2]); acc[i][2]=fmaf(hv.y,w1.z,acc[i][2]); \
  acc[i][2]=fmaf(hv.z,w2.z,acc[i][2]); acc[i][2]=fmaf(hv.w,w3.z,acc[i][2]); \
  acc[i][3]=fmaf(hv.x,w0.w,acc[i][3]); acc[i][3]=fmaf(hv.y,w1.w,acc[i][3]); \
  acc[i][3]=fmaf(hv.z,w2.w,acc[i][3]); acc[i][3]=fmaf(hv.w,w3.w,acc[i][3]);

__global__ __launch_bounds__(256) void rnn_persist(
    const float* __restrict__ Whh, const float* __restrict__ xproj,
    float* __restrict__ hbuf0, float* __restrict__ hbuf1,
    unsigned* __restrict__ flags) {
  extern __shared__ float lds[];
  float* Ws = lds;                  // [1024][32] transposed W slice
  float* Hs = lds + 1024 * 32;      // [8][1024] b-major, swizzled blocks
  float* red = Hs;                  // alias (needs 256*20 = 5120 f)
  float4* Hs4 = (float4*)Hs;
  const float4* Ws4 = (const float4*)Ws;

  const int tid = threadIdx.x;
  const int wg = blockIdx.x;
  const int bgrp = wg & 7;
  const int nslc = wg >> 3;
  const int nbase = nslc << 5;
  const int bbase = bgrp << 3;
  // flags: 8 domains x 32 WGs, 128B (32 dwords) stride per flag
  unsigned* myflag = flags + (bgrp << 10) + (nslc << 5);
  unsigned* pollp  = flags + (bgrp << 10) + ((tid & 31) << 5);

  // ---- one-time: W_hh slice transposed into LDS (Ws[k][hl] = W[nbase+hl][k])
  {
    const float4* W4 = (const float4*)Whh;
    for (int f = tid; f < 32 * 256; f += 256) {
      int hl = f >> 8;
      int kq = f & 255;
      float4 v = W4[(nbase + hl) * 256 + kq];
      int k = kq << 2;
      Ws[(k + 0) * 32 + hl] = v.x;
      Ws[(k + 1) * 32 + hl] = v.y;
      Ws[(k + 2) * 32 + hl] = v.z;
      Ws[(k + 3) * 32 + hl] = v.w;
    }
  }
  // ---- zero own h0 slice (coherent stores) and publish epoch 1 ----
  const int b_o = tid >> 5, n_o = tid & 31;
  const int gb = bbase + b_o, gn = nbase + n_o;
  __hip_atomic_store(&hbuf0[(gb << 10) + gn], 0.0f,
                     __ATOMIC_RELAXED, __HIP_MEMORY_SCOPE_AGENT);
  __syncthreads();   // vmcnt(0) drain: zeros acked at L3
  if (tid == 0)
    __hip_atomic_store(myflag, 1u, __ATOMIC_RELAXED, __HIP_MEMORY_SCOPE_AGENT);

  const int kp  = tid >> 4;          // 0..15 k-chunk (64 wide)
  const int hd8 = (tid >> 1) & 7;    // hd block
  const int b4  = tid & 1;           // batch half
  const int cbase = (((n_o >> 2) << 1) | (b_o >> 2)) * 20 + ((b_o & 3) << 2) + (n_o & 3);

  float* hc = hbuf0;
  float* hn = hbuf1;

#pragma unroll 1
  for (int t = 0; t < 512; ++t) {
    // this step's xproj value: plain cached load (written by a prior kernel),
    // issued before the wait so its latency overlaps the poll
    const float xpv = xproj[((t << 6) + gb) * 1024 + gn];

    // 0. wait: all 32 domain flags >= t+1 (h(t) published everywhere)
    if (tid < 64) {
      const unsigned tgt = (unsigned)t + 1u;
      while (!__all(__hip_atomic_load(pollp, __ATOMIC_RELAXED,
                                      __HIP_MEMORY_SCOPE_AGENT) >= tgt))
        __builtin_amdgcn_s_sleep(1);
    }
    __syncthreads();   // fan-out + ordering fence (compiler + waitcnt)

    // 1. stage h rows [bbase..bbase+8) into Hs (coherent scalar loads,
    //    swizzled b128 LDS stores). Layout identical to R5.
    {
      const float* hb = hc + (bbase << 10) + (tid << 2);
#pragma unroll
      for (int it = 0; it < 8; ++it) {
        const float* p = hb + (it << 10);
        float v0 = __hip_atomic_load(p + 0, __ATOMIC_RELAXED, __HIP_MEMORY_SCOPE_AGENT);
        float v1 = __hip_atomic_load(p + 1, __ATOMIC_RELAXED, __HIP_MEMORY_SCOPE_AGENT);
        float v2 = __hip_atomic_load(p + 2, __ATOMIC_RELAXED, __HIP_MEMORY_SCOPE_AGENT);
        float v3 = __hip_atomic_load(p + 3, __ATOMIC_RELAXED, __HIP_MEMORY_SCOPE_AGENT);
        Hs4[((it << 8) | tid) ^ ((tid >> 4) & 7)] = make_float4(v0, v1, v2, v3);
      }
    }
    __syncthreads();

    // 2. 4b x 4hd microtile over this thread's 64-k chunk, k-vectorized by 4
    float acc[4][4] = {};
#pragma unroll
    for (int q = 0; q < 16; ++q) {
      const int k0 = (kp << 6) + (q << 2);
      const int kb = k0 >> 2;
      const int sw = kp & 7;
      float4 h0v = Hs4[((((b4 << 2) + 0) << 8) | kb) ^ sw];
      float4 h1v = Hs4[((((b4 << 2) + 1) << 8) | kb) ^ sw];
      float4 h2v = Hs4[((((b4 << 2) + 2) << 8) | kb) ^ sw];
      float4 h3v = Hs4[((((b4 << 2) + 3) << 8) | kb) ^ sw];
      float4 w0 = Ws4[(k0 + 0) * 8 + hd8];
      float4 w1 = Ws4[(k0 + 1) * 8 + hd8];
      float4 w2 = Ws4[(k0 + 2) * 8 + hd8];
      float4 w3 = Ws4[(k0 + 3) * 8 + hd8];
      DO_B(0, h0v)
      DO_B(1, h1v)
      DO_B(2, h2v)
      DO_B(3, h3v)
    }
    __syncthreads();   // everyone done reading Hs before red overwrites it

    // 3. spill partials, stride 20 floats (bank-balanced b128 stores)
    float4* m4 = (float4*)(red + tid * 20);
    m4[0] = make_float4(acc[0][0], acc[0][1], acc[0][2], acc[0][3]);
    m4[1] = make_float4(acc[1][0], acc[1][1], acc[1][2], acc[1][3]);
    m4[2] = make_float4(acc[2][0], acc[2][1], acc[2][2], acc[2][3]);
    m4[3] = make_float4(acc[3][0], acc[3][1], acc[3][2], acc[3][3]);
    __syncthreads();

    // 4. reduce 16 k-chunks, tanh, write h_next (coherent), publish
    float sum = 0.0f;
#pragma unroll
    for (int kp2 = 0; kp2 < 16; ++kp2)
      sum += red[kp2 * 320 + cbase];
    __hip_atomic_store(hn + (gb << 10) + gn, tanhf(xpv + sum),
                       __ATOMIC_RELAXED, __HIP_MEMORY_SCOPE_AGENT);
    __syncthreads();   // vmcnt(0) drain: slice acked at L3 before flag
    if (tid == 0)
      __hip_atomic_store(myflag, (unsigned)t + 2u,
                         __ATOMIC_RELAXED, __HIP_MEMORY_SCOPE_AGENT);

    float* tmp = hc; hc = hn; hn = tmp;
  }
  // final h in hbuf0 (even number of swaps)
}

// ---------------------------------------------------------------------------
// Kernel 3: head GEMM: C[64][N] = A[64][K] * Bm[N][K]^T + bias[N]
// ---------------------------------------------------------------------------
__global__ __launch_bounds__(256) void head_gemm(
    const float* __restrict__ A, const float* __restrict__ Bm,
    const float* __restrict__ bias, float* __restrict__ C, int N, int K) {
  __shared__ float As[16][68];
  __shared__ float Bs[16][68];
  const int tid = threadIdx.x;
  const int n0 = blockIdx.x * 64;
  const int r = tid >> 2;
  const int c4 = (tid & 3) << 2;
  const int ty = tid >> 4, tx = tid & 15;
  float acc[4][4] = {};
  const float4* A4 = (const float4*)A;
  const float4* B4 = (const float4*)Bm;
  const int K4 = K >> 2;

  for (int k0 = 0; k0 < K; k0 += 16) {
    const int kq = (k0 >> 2) + (tid & 3);
    float4 av = A4[r * K4 + kq];
    float4 bv = B4[(n0 + r) * K4 + kq];
    __syncthreads();
    As[c4 + 0][r] = av.x; As[c4 + 1][r] = av.y; As[c4 + 2][r] = av.z; As[c4 + 3][r] = av.w;
    Bs[c4 + 0][r] = bv.x; Bs[c4 + 1][r] = bv.y; Bs[c4 + 2][r] = bv.z; Bs[c4 + 3][r] = bv.w;
    __syncthreads();
#pragma unroll
    for (int kk = 0; kk < 16; ++kk) {
      float4 a = *(const float4*)&As[kk][ty << 2];
      float4 b = *(const float4*)&Bs[kk][tx << 2];
      acc[0][0] = fmaf(a.x, b.x, acc[0][0]); acc[0][1] = fmaf(a.x, b.y, acc[0][1]);
      acc[0][2] = fmaf(a.x, b.z, acc[0][2]); acc[0][3] = fmaf(a.x, b.w, acc[0][3]);
      acc[1][0] = fmaf(a.y, b.x, acc[1][0]); acc[1][1] = fmaf(a.y, b.y, acc[1][1]);
      acc[1][2] = fmaf(a.y, b.z, acc[1][2]); acc[1][3] = fmaf(a.y, b.w, acc[1][3]);
      acc[2][0] = fmaf(a.z, b.x, acc[2][0]); acc[2][1] = fmaf(a.z, b.y, acc[2][1]);
      acc[2][2] = fmaf(a.z, b.z, acc[2][2]); acc[2][3] = fmaf(a.z, b.w, acc[2][3]);
      acc[3][0] = fmaf(a.w, b.x, acc[3][0]); acc[3][1] = fmaf(a.w, b.y, acc[3][1]);
      acc[3][2] = fmaf(a.w, b.z, acc[3][2]); acc[3][3] = fmaf(a.w, b.w, acc[3][3]);
    }
  }
  float4 bv = *(const float4*)&bias[n0 + (tx << 2)];
  float bs[4] = {bv.x, bv.y, bv.z, bv.w};
#pragma unroll
  for (int i = 0; i < 4; ++i) {
    float4 o;
    o.x = acc[i][0] + bs[0]; o.y = acc[i][1] + bs[1];
    o.z = acc[i][2] + bs[2]; o.w = acc[i][3] + bs[3];
    *(float4*)&C[((ty << 2) + i) * N + n0 + (tx << 2)] = o;
  }
}

// ---------------------------------------------------------------------------
extern "C" void kernel_launch(void* const* d_in, const int* in_sizes, int n_in,
                              void* d_out, int out_size, void* d_ws, size_t ws_size,
                              hipStream_t stream) {
  const float* x    = (const float*)d_in[0];
  const float* Wih  = (const float*)d_in[1];
  const float* bih  = (const float*)d_in[2];
  const float* Whh  = (const float*)d_in[3];
  const float* bhh  = (const float*)d_in[4];
  const float* Wfc  = (const float*)d_in[5];
  const float* bfc  = (const float*)d_in[6];
  const float* Wclf = (const float*)d_in[7];
  const float* bclf = (const float*)d_in[8];
  float* out = (float*)d_out;

  float* ws = (float*)d_ws;
  float* xp = ws;                      // 33,554,432 f (128 MB), layout [T][B][H]
  float* h0 = ws + 33554432;           // 65,536 f
  float* h1 = h0 + 65536;              // 65,536 f
  float* y1 = h1 + 65536;              // 65,536 f

  // epoch flags: 8 domains x 32 WGs x 128B = 32KB, in d_out's first 32KB
  // (poisoned each call -> memset; heads fully overwrite d_out afterwards)
  unsigned* flags = (unsigned*)d_out;
  hipMemsetAsync(flags, 0, 8 * 32 * 32 * sizeof(unsigned), stream);

  // Phase 1: input projection, transposed to [T][B][H]
  xproj_gemm<<<dim3(8, 256), 256, 0, stream>>>(x, Wih, bih, bhh, xp);

  // Phase 2: persistent recurrence (160 KiB dynamic LDS, coop for residency)
  hipFuncSetAttribute((const void*)rnn_persist,
                      hipFuncAttributeMaxDynamicSharedMemorySize, 163840);
  void* args[] = {(void*)&Whh, (void*)&xp, (void*)&h0, (void*)&h1, (void*)&flags};
  hipLaunchCooperativeKernel((const void*)rnn_persist, dim3(256), dim3(256),
                             args, 163840, stream);

  // Phase 3: head
  head_gemm<<<dim3(16), 256, 0, stream>>>(h0, Wfc, bfc, y1, 1024, 1024);
  head_gemm<<<dim3(4),  256, 0, stream>>>(y1, Wclf, bclf, out, 256, 1024);
}